// Round 1
// baseline (1945.140 us; speedup 1.0000x reference)
//
#include <hip/hip_runtime.h>
#include <math.h>

// GPN pointer-network decode, MI355X fp32 implementation.
// N=128 regions, B=512 batch, D=128, T=16 steps.
//
// Structure:
//   k_embed  : emb[n,b,d] = data[n,b,:4] @ node_embed
//   k_mean   : mean over n of [N,B,D] -> [B,D]
//   k_agg    : relu(mean @ aggW^T + aggb) -> [B,D]
//   k_gemm<0>: gated layer  out = r*(in@W^T+b) + (1-r)*yagg[b]   ([N*B,128]@[128,128])
//   k_gemm<1>: ref proj     eT[b][n][o] = in[n,b,:]@Wref^T + bref (stored [B,N,D] for
//              coalesced writes; decode transposes into LDS)
//   k_decode : persistent per-batch-element decode, 1 block per b, T=16 steps fused.
//              e-tables live in LDS (128x132 padded) for all steps.

#define NREG   128
#define BATCH  512
#define DIM    128
#define TSTEPS 16
#define NEGV   (-1e9f)

// ---------------- K1: node embedding ----------------
__global__ __launch_bounds__(256) void k_embed(const float* __restrict__ data,
                                               const float* __restrict__ node_embed,
                                               float* __restrict__ emb) {
    int idx = blockIdx.x * 256 + threadIdx.x;  // covers N*B*D exactly
    int d  = idx & 127;
    int nb = idx >> 7;
    float4 dv = *(const float4*)(data + nb * 4);
    emb[idx] = dv.x * node_embed[d] + dv.y * node_embed[DIM + d]
             + dv.z * node_embed[2 * DIM + d] + dv.w * node_embed[3 * DIM + d];
}

// ---------------- K2: mean over nodes ----------------
__global__ __launch_bounds__(128) void k_mean(const float* __restrict__ src,
                                              float* __restrict__ dst) {
    int b = blockIdx.x, d = threadIdx.x;
    float acc = 0.f;
    for (int n = 0; n < NREG; n++) acc += src[((long)n * BATCH + b) * DIM + d];
    dst[b * DIM + d] = acc * (1.f / NREG);
}

// ---------------- K3: aggregated-gate path ----------------
__global__ __launch_bounds__(128) void k_agg(const float* __restrict__ meanb,
                                             const float* __restrict__ aggW,
                                             const float* __restrict__ aggB,
                                             float* __restrict__ yagg) {
    __shared__ __align__(16) float m[DIM];
    int b = blockIdx.x, o = threadIdx.x;
    m[o] = meanb[b * DIM + o];
    __syncthreads();
    const float4* w = (const float4*)(aggW + o * DIM);
    float acc = aggB[o];
#pragma unroll
    for (int k = 0; k < DIM / 4; k++) {
        float4 wv = w[k];
        float4 mv = *(const float4*)&m[k * 4];
        acc += wv.x * mv.x + wv.y * mv.y + wv.z * mv.z + wv.w * mv.w;
    }
    yagg[b * DIM + o] = fmaxf(acc, 0.f);
}

// ---------------- K4/K5: tiled fp32 GEMM ----------------
// in: [M=N*B, 128] row-major (row = n*B + b), W: [128 out, 128 in]
// MODE 0: out[row, o] = r*(acc + bias[o]) + (1-r)*yagg[b][o]        (layout [M,128])
// MODE 1: out[b*N*D + n*D + o] = acc + bias[o]                      (layout [B,N,D])
#define BM 32
template <int MODE>
__global__ __launch_bounds__(256) void k_gemm(const float* __restrict__ in,
                                              const float* __restrict__ W,
                                              const float* __restrict__ bias,
                                              const float* __restrict__ rg,
                                              const float* __restrict__ yagg,
                                              float* __restrict__ out) {
    __shared__ __align__(16) float As[BM][DIM];
    __shared__ __align__(16) float Ws[DIM][132];  // +4 pad: 4-way instead of 32-way conflicts
    int t = threadIdx.x;
    long row0 = (long)blockIdx.x * BM;

    for (int i = t * 4; i < DIM * DIM; i += 1024) {
        float4 v = *(const float4*)(W + i);
        int o = i >> 7, k = i & 127;
        *(float4*)(&Ws[o][k]) = v;
    }
    for (int i = t * 4; i < BM * DIM; i += 1024) {
        int r = i >> 7, k = i & 127;
        *(float4*)(&As[r][k]) = *(const float4*)(in + (row0 + r) * DIM + k);
    }
    __syncthreads();

    int tc = t & 31;   // col group: cols tc + 32*j
    int tr = t >> 5;   // row group: rows tr*4 + i
    float acc[4][4];
#pragma unroll
    for (int i = 0; i < 4; i++)
#pragma unroll
        for (int j = 0; j < 4; j++) acc[i][j] = 0.f;

#pragma unroll 4
    for (int k = 0; k < DIM; k += 4) {
        float4 a[4], w[4];
#pragma unroll
        for (int i = 0; i < 4; i++) a[i] = *(const float4*)(&As[tr * 4 + i][k]);
#pragma unroll
        for (int j = 0; j < 4; j++) w[j] = *(const float4*)(&Ws[tc + 32 * j][k]);
#pragma unroll
        for (int i = 0; i < 4; i++)
#pragma unroll
            for (int j = 0; j < 4; j++)
                acc[i][j] += a[i].x * w[j].x + a[i].y * w[j].y +
                             a[i].z * w[j].z + a[i].w * w[j].w;
    }

    if (MODE == 0) {
        float r = rg[0];
#pragma unroll
        for (int i = 0; i < 4; i++) {
            long row = row0 + tr * 4 + i;
            int bb = (int)(row & (BATCH - 1));
#pragma unroll
            for (int j = 0; j < 4; j++) {
                int col = tc + 32 * j;
                out[row * DIM + col] =
                    r * (acc[i][j] + bias[col]) + (1.f - r) * yagg[bb * DIM + col];
            }
        }
    } else {
#pragma unroll
        for (int i = 0; i < 4; i++) {
            long row = row0 + tr * 4 + i;
            int nn = (int)(row >> 9);          // row = n*512 + b
            int bb = (int)(row & (BATCH - 1));
#pragma unroll
            for (int j = 0; j < 4; j++) {
                int col = tc + 32 * j;
                out[(long)bb * (NREG * DIM) + nn * DIM + col] = acc[i][j] + bias[col];
            }
        }
    }
}

// ---------------- K6: persistent decode, one block per batch element ----------------
__global__ __launch_bounds__(256) void k_decode(
    const float* __restrict__ emb,   // [N,B,D]
    const float* __restrict__ egT,   // [B,N,D]  (e_glm transposed)
    const float* __restrict__ epT,   // [B,N,D]  (e_ptr transposed)
    const float* __restrict__ init_ph,
    const float* __restrict__ Wih, const float* __restrict__ Whh,
    const float* __restrict__ bih, const float* __restrict__ bhh,
    const float* __restrict__ glm_Wq, const float* __restrict__ glm_bq,
    const float* __restrict__ glm_v,
    const float* __restrict__ ptr_Wq, const float* __restrict__ ptr_bq,
    const float* __restrict__ ptr_v,
    float* __restrict__ out)         // [T,B,N]
{
    // 132-float row pitch: conflict-free for both [d][n] (lanes over n) and
    // per-thread row-float4 (lanes over d -> 4-way) access patterns.
    __shared__ __align__(16) float Eg[DIM][132];
    __shared__ __align__(16) float Ep[DIM][132];
    __shared__ __align__(16) float hS[DIM], cS[DIM], xS[DIM], qS[DIM];
    __shared__ __align__(16) float lS[NREG], pS[NREG], gS[DIM];
    __shared__ __align__(16) float gates[4 * DIM];
    __shared__ __align__(16) float vg[DIM], vp[DIM];
    __shared__ int visited[NREG];
    __shared__ float mS, sS;
    __shared__ int selS;

    const int t = threadIdx.x;
    const int b = blockIdx.x;

    // stage e-tables (transpose [n][d] -> [d][n])
    const float* eg = egT + (long)b * (NREG * DIM);
    const float* ep = epT + (long)b * (NREG * DIM);
    for (int i = t; i < NREG * DIM; i += 256) {
        int n = i >> 7, d = i & 127;
        Eg[d][n] = eg[i];
        Ep[d][n] = ep[i];
    }
    if (t < DIM) {
        hS[t] = 0.f; cS[t] = 0.f; xS[t] = init_ph[t];
        visited[t] = 0;
        vg[t] = glm_v[t]; vp[t] = ptr_v[t];
    }
    __syncthreads();

    for (int step = 0; step < TSTEPS; step++) {
        // ---- LSTM gates: 2 rows per thread ----
        for (int g = t; g < 4 * DIM; g += 256) {
            const float4* wi = (const float4*)(Wih + g * DIM);
            const float4* wh = (const float4*)(Whh + g * DIM);
            float acc = bih[g] + bhh[g];
#pragma unroll 8
            for (int k = 0; k < DIM / 4; k++) {
                float4 a = wi[k], xk = *(const float4*)&xS[k * 4];
                float4 c2 = wh[k], hk = *(const float4*)&hS[k * 4];
                acc += a.x * xk.x + a.y * xk.y + a.z * xk.z + a.w * xk.w;
                acc += c2.x * hk.x + c2.y * hk.y + c2.z * hk.z + c2.w * hk.w;
            }
            gates[g] = acc;
        }
        __syncthreads();
        // ---- LSTM pointwise (torch gate order i,f,g,o) ----
        if (t < DIM) {
            float ig = 1.f / (1.f + expf(-gates[t]));
            float fg = 1.f / (1.f + expf(-gates[DIM + t]));
            float gg = tanhf(gates[2 * DIM + t]);
            float og = 1.f / (1.f + expf(-gates[3 * DIM + t]));
            float cn = fg * cS[t] + ig * gg;
            cS[t] = cn;
            hS[t] = og * tanhf(cn);
        }
        __syncthreads();
        // ---- glimpse query: qq = h @ glm_Wq^T + glm_bq ----
        if (t < DIM) {
            const float4* w = (const float4*)(glm_Wq + t * DIM);
            float acc = glm_bq[t];
#pragma unroll 8
            for (int k = 0; k < DIM / 4; k++) {
                float4 wv = w[k], hv = *(const float4*)&hS[k * 4];
                acc += wv.x * hv.x + wv.y * hv.y + wv.z * hv.z + wv.w * hv.w;
            }
            qS[t] = acc;
        }
        __syncthreads();
        // ---- glimpse logits: lg[n] = sum_d vg[d]*tanh(qq[d]+Eg[d][n]) ----
        if (t < NREG) {
            float acc = 0.f;
            for (int d = 0; d < DIM; d++) acc += vg[d] * tanhf(qS[d] + Eg[d][t]);
            lS[t] = visited[t] ? NEGV : acc;
        }
        __syncthreads();
        // ---- softmax over n ----
        if (t < 64) {
            float m = fmaxf(lS[t], lS[t + 64]);
            for (int off = 32; off; off >>= 1) m = fmaxf(m, __shfl_xor(m, off, 64));
            if (t == 0) mS = m;
        }
        __syncthreads();
        if (t < NREG) pS[t] = expf(lS[t] - mS);
        __syncthreads();
        if (t < 64) {
            float s = pS[t] + pS[t + 64];
            for (int off = 32; off; off >>= 1) s += __shfl_xor(s, off, 64);
            if (t == 0) sS = s;
        }
        __syncthreads();
        // ---- glimpse combine: gl[d] = (sum_n Eg[d][n]*e[n]) / s ----
        if (t < DIM) {
            float acc = 0.f;
#pragma unroll 8
            for (int k = 0; k < NREG / 4; k++) {
                float4 ev = *(const float4*)&Eg[t][k * 4];
                float4 pv = *(const float4*)&pS[k * 4];
                acc += ev.x * pv.x + ev.y * pv.y + ev.z * pv.z + ev.w * pv.w;
            }
            gS[t] = acc / sS;
        }
        __syncthreads();
        // ---- pointer query: qq = gl @ ptr_Wq^T + ptr_bq ----
        if (t < DIM) {
            const float4* w = (const float4*)(ptr_Wq + t * DIM);
            float acc = ptr_bq[t];
#pragma unroll 8
            for (int k = 0; k < DIM / 4; k++) {
                float4 wv = w[k], gv = *(const float4*)&gS[k * 4];
                acc += wv.x * gv.x + wv.y * gv.y + wv.z * gv.z + wv.w * gv.w;
            }
            qS[t] = acc;
        }
        __syncthreads();
        // ---- pointer logits: lp[n] = 10*tanh(sum_d vp[d]*tanh(qq[d]+Ep[d][n])) ----
        if (t < NREG) {
            float acc = 0.f;
            for (int d = 0; d < DIM; d++) acc += vp[d] * tanhf(qS[d] + Ep[d][t]);
            float lp = 10.f * tanhf(acc);
            lS[t] = visited[t] ? NEGV : lp;
        }
        __syncthreads();
        // ---- log_softmax ----
        if (t < 64) {
            float m = fmaxf(lS[t], lS[t + 64]);
            for (int off = 32; off; off >>= 1) m = fmaxf(m, __shfl_xor(m, off, 64));
            if (t == 0) mS = m;
        }
        __syncthreads();
        if (t < NREG) pS[t] = expf(lS[t] - mS);
        __syncthreads();
        if (t < 64) {
            float s = pS[t] + pS[t + 64];
            for (int off = 32; off; off >>= 1) s += __shfl_xor(s, off, 64);
            if (t == 0) sS = logf(s);
        }
        __syncthreads();
        if (t < NREG)
            out[((long)step * BATCH + b) * NREG + t] = lS[t] - mS - sS;
        // ---- argmax (first-max tie-break like jnp.argmax) ----
        if (t < 64) {
            float v; int idx;
            float v1 = lS[t], v2 = lS[t + 64];
            if (v2 > v1) { v = v2; idx = t + 64; } else { v = v1; idx = t; }
            for (int off = 32; off; off >>= 1) {
                float ov = __shfl_xor(v, off, 64);
                int   oi = __shfl_xor(idx, off, 64);
                if (ov > v || (ov == v && oi < idx)) { v = ov; idx = oi; }
            }
            if (t == 0) selS = idx;
        }
        __syncthreads();
        // ---- update visited + next decoder input ----
        if (t < DIM) {
            int sel = selS;
            if (t == 0) visited[sel] = 1;
            xS[t] = emb[((long)sel * BATCH + b) * DIM + t];
        }
        __syncthreads();
    }
}

// ---------------- host launcher ----------------
extern "C" void kernel_launch(void* const* d_in, const int* in_sizes, int n_in,
                              void* d_out, int out_size, void* d_ws, size_t ws_size,
                              hipStream_t stream) {
    const float* data       = (const float*)d_in[0];
    const float* node_embed = (const float*)d_in[1];
    const float* init_ph    = (const float*)d_in[2];
    const float* W1w = (const float*)d_in[3];  const float* W1b = (const float*)d_in[4];
    const float* W2w = (const float*)d_in[5];  const float* W2b = (const float*)d_in[6];
    const float* W3w = (const float*)d_in[7];  const float* W3b = (const float*)d_in[8];
    const float* A1w = (const float*)d_in[9];  const float* A1b = (const float*)d_in[10];
    const float* A2w = (const float*)d_in[11]; const float* A2b = (const float*)d_in[12];
    const float* A3w = (const float*)d_in[13]; const float* A3b = (const float*)d_in[14];
    const float* r1  = (const float*)d_in[15];
    const float* r2  = (const float*)d_in[16];
    const float* r3  = (const float*)d_in[17];
    const float* Wih = (const float*)d_in[18]; const float* Whh = (const float*)d_in[19];
    const float* bih = (const float*)d_in[20]; const float* bhh = (const float*)d_in[21];
    const float* pWq = (const float*)d_in[22]; const float* pbq = (const float*)d_in[23];
    const float* pWr = (const float*)d_in[24]; const float* pbr = (const float*)d_in[25];
    const float* pv  = (const float*)d_in[26];
    const float* gWq = (const float*)d_in[27]; const float* gbq = (const float*)d_in[28];
    const float* gWr = (const float*)d_in[29]; const float* gbr = (const float*)d_in[30];
    const float* gv  = (const float*)d_in[31];
    float* out = (float*)d_out;

    const long SZ = (long)NREG * BATCH * DIM;  // 8388608 floats per big buffer
    float* ws    = (float*)d_ws;
    float* emb   = ws;
    float* bufA  = ws + SZ;
    float* bufB  = ws + 2 * SZ;
    float* bufC  = ws + 3 * SZ;
    float* meanb = ws + 4 * SZ;
    float* yagg  = meanb + BATCH * DIM;

    const int gemm_grid = (NREG * BATCH) / BM;  // 2048

    k_embed<<<(int)(SZ / 256), 256, 0, stream>>>(data, node_embed, emb);

    // layer 1: emb -> bufA
    k_mean<<<BATCH, 128, 0, stream>>>(emb, meanb);
    k_agg<<<BATCH, 128, 0, stream>>>(meanb, A1w, A1b, yagg);
    k_gemm<0><<<gemm_grid, 256, 0, stream>>>(emb, W1w, W1b, r1, yagg, bufA);
    // layer 2: bufA -> bufB
    k_mean<<<BATCH, 128, 0, stream>>>(bufA, meanb);
    k_agg<<<BATCH, 128, 0, stream>>>(meanb, A2w, A2b, yagg);
    k_gemm<0><<<gemm_grid, 256, 0, stream>>>(bufA, W2w, W2b, r2, yagg, bufB);
    // layer 3: bufB -> bufA
    k_mean<<<BATCH, 128, 0, stream>>>(bufB, meanb);
    k_agg<<<BATCH, 128, 0, stream>>>(meanb, A3w, A3b, yagg);
    k_gemm<0><<<gemm_grid, 256, 0, stream>>>(bufB, W3w, W3b, r3, yagg, bufA);
    // ref projections (stored [B,N,D]): e_ptr -> bufB, e_glm -> bufC
    k_gemm<1><<<gemm_grid, 256, 0, stream>>>(bufA, pWr, pbr, nullptr, nullptr, bufB);
    k_gemm<1><<<gemm_grid, 256, 0, stream>>>(bufA, gWr, gbr, nullptr, nullptr, bufC);
    // fused 16-step decode
    k_decode<<<BATCH, 256, 0, stream>>>(emb, bufC, bufB, init_ph, Wih, Whh, bih, bhh,
                                        gWq, gbq, gv, pWq, pbq, pv, out);
}

// Round 2
// 904.400 us; speedup vs baseline: 2.1508x; 2.1508x over previous
//
#include <hip/hip_runtime.h>
#include <math.h>

// GPN pointer-network decode, MI355X fp32. N=128, B=512, D=128, T=16.
// R2: decode occupancy 2 blocks/CU (Eg-only in LDS, Ep streamed from L2 in
// [B,D,N] layout), coalesced k-major LSTM/query weights (prep transpose),
// hw-exp fast tanh/sigmoid, all-256-thread phases, merged softmax waves.

#define NREG   128
#define BATCH  512
#define DIM    128
#define TSTEPS 16
#define NEGV   (-1e9f)
#define LOG2E  1.4426950408889634f

__device__ __forceinline__ float fexp2(float x) { return __builtin_amdgcn_exp2f(x); }
__device__ __forceinline__ float frcp(float x)  { return __builtin_amdgcn_rcpf(x); }
// tanh(x) = 1 - 2/(1+e^{2x}); saturates correctly at +/-inf (exp2->inf, rcp->0)
__device__ __forceinline__ float fast_tanh(float x) {
    return 1.f - 2.f * frcp(1.f + fexp2(2.8853900817779268f * x));
}
__device__ __forceinline__ float fast_sig(float x) {
    return frcp(1.f + fexp2(-LOG2E * x));
}
__device__ __forceinline__ float fast_exp(float x) { return fexp2(LOG2E * x); }
__device__ __forceinline__ float fast_log(float x) {
    return __builtin_amdgcn_logf(x) * 0.6931471805599453f;
}

// ---------------- K1: node embedding ----------------
__global__ __launch_bounds__(256) void k_embed(const float* __restrict__ data,
                                               const float* __restrict__ node_embed,
                                               float* __restrict__ emb) {
    int idx = blockIdx.x * 256 + threadIdx.x;
    int d  = idx & 127;
    int nb = idx >> 7;
    float4 dv = *(const float4*)(data + nb * 4);
    emb[idx] = dv.x * node_embed[d] + dv.y * node_embed[DIM + d]
             + dv.z * node_embed[2 * DIM + d] + dv.w * node_embed[3 * DIM + d];
}

// ---------------- K2: mean over nodes ----------------
__global__ __launch_bounds__(128) void k_mean(const float* __restrict__ src,
                                              float* __restrict__ dst) {
    int b = blockIdx.x, d = threadIdx.x;
    float a0 = 0.f, a1 = 0.f;
    for (int n = 0; n < NREG; n += 2) {
        a0 += src[((long)n * BATCH + b) * DIM + d];
        a1 += src[((long)(n + 1) * BATCH + b) * DIM + d];
    }
    dst[b * DIM + d] = (a0 + a1) * (1.f / NREG);
}

// ---------------- K3: aggregated-gate path ----------------
__global__ __launch_bounds__(128) void k_agg(const float* __restrict__ meanb,
                                             const float* __restrict__ aggW,
                                             const float* __restrict__ aggB,
                                             float* __restrict__ yagg) {
    __shared__ __align__(16) float m[DIM];
    int b = blockIdx.x, o = threadIdx.x;
    m[o] = meanb[b * DIM + o];
    __syncthreads();
    const float4* w = (const float4*)(aggW + o * DIM);
    float acc = aggB[o];
#pragma unroll
    for (int k = 0; k < DIM / 4; k++) {
        float4 wv = w[k];
        float4 mv = *(const float4*)&m[k * 4];
        acc += wv.x * mv.x + wv.y * mv.y + wv.z * mv.z + wv.w * mv.w;
    }
    yagg[b * DIM + o] = fmaxf(acc, 0.f);
}

// ---------------- K4: prep — transposed weight layouts for decode ----------------
// WcombT[256][512]: rows 0..127 = Wih^T, 128..255 = Whh^T (k-major, g coalesced)
// bcomb[512] = bih + bhh;  gWqT/pWqT[128][128] = Wq^T ([i][o])
__global__ __launch_bounds__(256) void k_prep(const float* __restrict__ Wih,
                                              const float* __restrict__ Whh,
                                              const float* __restrict__ bih,
                                              const float* __restrict__ bhh,
                                              const float* __restrict__ gWq,
                                              const float* __restrict__ pWq,
                                              float* __restrict__ WcombT,
                                              float* __restrict__ bcomb,
                                              float* __restrict__ gWqT,
                                              float* __restrict__ pWqT) {
    int blk = blockIdx.x, t = threadIdx.x;
    if (blk < 256) {
        int k = blk;
        const float* W = (k < 128) ? Wih : Whh;
        int kk = k & 127;
        WcombT[k * 512 + t]       = W[t * 128 + kk];
        WcombT[k * 512 + 256 + t] = W[(256 + t) * 128 + kk];
    } else if (blk == 256) {
        bcomb[t] = bih[t] + bhh[t];
        bcomb[256 + t] = bih[256 + t] + bhh[256 + t];
    } else if (blk < 257 + 64) {
        int idx = (blk - 257) * 256 + t;
        int i = idx >> 7, o = idx & 127;
        gWqT[i * 128 + o] = gWq[o * 128 + i];
    } else {
        int idx = (blk - 321) * 256 + t;
        int i = idx >> 7, o = idx & 127;
        pWqT[i * 128 + o] = pWq[o * 128 + i];
    }
}

// ---------------- K5: [B][N][D] -> [B][D][N] transpose (e_ptr) ----------------
__global__ __launch_bounds__(256) void k_transp(const float* __restrict__ in,
                                                float* __restrict__ outp) {
    __shared__ float tile[32][33];
    int bid = blockIdx.x;
    int b = bid >> 4;
    int tidx = bid & 15;
    int n0 = (tidx >> 2) * 32, d0 = (tidx & 3) * 32;
    int tx = threadIdx.x & 31, ty = threadIdx.x >> 5;
    const float* src = in + ((long)b * NREG + n0) * DIM + d0;
    for (int r = ty; r < 32; r += 8) tile[r][tx] = src[r * DIM + tx];
    __syncthreads();
    float* dst = outp + ((long)b * DIM + d0) * NREG + n0;
    for (int r = ty; r < 32; r += 8) dst[r * NREG + tx] = tile[tx][r];
}

// ---------------- K6: tiled fp32 GEMM ----------------
// in: [M=N*B, 128] (row = n*B + b), W: [128 out, 128 in]
// MODE 0: out[row,o] = r*(acc+bias) + (1-r)*yagg[b][o]   ([M,128])
// MODE 1: out[b*N*D + n*D + o] = acc + bias              ([B,N,D])
#define BM 16
template <int MODE>
__global__ __launch_bounds__(256) void k_gemm(const float* __restrict__ in,
                                              const float* __restrict__ W,
                                              const float* __restrict__ bias,
                                              const float* __restrict__ rg,
                                              const float* __restrict__ yagg,
                                              float* __restrict__ out) {
    __shared__ __align__(16) float As[BM][DIM];     // 8 KB
    __shared__ __align__(16) float Ws[DIM][132];    // 67.6 KB -> total 75.6 KB, 2 blk/CU
    int t = threadIdx.x;
    long row0 = (long)blockIdx.x * BM;

    for (int i = t * 4; i < DIM * DIM; i += 1024) {
        float4 v = *(const float4*)(W + i);
        int o = i >> 7, k = i & 127;
        *(float4*)(&Ws[o][k]) = v;
    }
    for (int i = t * 4; i < BM * DIM; i += 1024) {
        int r = i >> 7, k = i & 127;
        *(float4*)(&As[r][k]) = *(const float4*)(in + (row0 + r) * DIM + k);
    }
    __syncthreads();

    int tc = t & 31;   // cols tc + 32*j
    int tr = t >> 5;   // rows tr*2 + i
    float acc[2][4];
#pragma unroll
    for (int i = 0; i < 2; i++)
#pragma unroll
        for (int j = 0; j < 4; j++) acc[i][j] = 0.f;

#pragma unroll 4
    for (int k = 0; k < DIM; k += 4) {
        float4 a[2], w[4];
#pragma unroll
        for (int i = 0; i < 2; i++) a[i] = *(const float4*)(&As[tr * 2 + i][k]);
#pragma unroll
        for (int j = 0; j < 4; j++) w[j] = *(const float4*)(&Ws[tc + 32 * j][k]);
#pragma unroll
        for (int i = 0; i < 2; i++)
#pragma unroll
            for (int j = 0; j < 4; j++)
                acc[i][j] += a[i].x * w[j].x + a[i].y * w[j].y +
                             a[i].z * w[j].z + a[i].w * w[j].w;
    }

    if (MODE == 0) {
        float r = rg[0];
#pragma unroll
        for (int i = 0; i < 2; i++) {
            long row = row0 + tr * 2 + i;
            int bb = (int)(row & (BATCH - 1));
#pragma unroll
            for (int j = 0; j < 4; j++) {
                int col = tc + 32 * j;
                out[row * DIM + col] =
                    r * (acc[i][j] + bias[col]) + (1.f - r) * yagg[bb * DIM + col];
            }
        }
    } else {
#pragma unroll
        for (int i = 0; i < 2; i++) {
            long row = row0 + tr * 2 + i;
            int nn = (int)(row >> 9);
            int bb = (int)(row & (BATCH - 1));
#pragma unroll
            for (int j = 0; j < 4; j++) {
                int col = tc + 32 * j;
                out[(long)bb * (NREG * DIM) + nn * DIM + col] = acc[i][j] + bias[col];
            }
        }
    }
}

// ---------------- K7: persistent decode, 1 block / batch element, 2 blk/CU ----------------
__global__ __launch_bounds__(256, 2) void k_decode(
    const float* __restrict__ emb,     // [N,B,D]
    const float* __restrict__ egT,     // [B,N,D]  e_glm
    const float* __restrict__ epT2,    // [B,D,N]  e_ptr (transposed)
    const float* __restrict__ init_ph,
    const float* __restrict__ WcombT,  // [256][512]
    const float* __restrict__ bcomb,   // [512]
    const float* __restrict__ gWqT, const float* __restrict__ glm_bq,
    const float* __restrict__ glm_v,
    const float* __restrict__ pWqT, const float* __restrict__ ptr_bq,
    const float* __restrict__ ptr_v,
    float* __restrict__ out)           // [T,B,N]
{
    // pitch-129 rows: bank = (129n+d)%32 = (n+d)%32 -> conflict-free for
    // lanes-over-n (logits) AND lanes-over-d (combine) scalar access.
    __shared__ float En[NREG][129];          // 66 KB, e_glm resident all steps
    __shared__ float xh[256];                // [x ; h]
    __shared__ float cS[DIM];
    __shared__ float gates[4 * DIM];
    __shared__ float qpart[2][DIM];
    __shared__ float lpart[2][NREG];
    __shared__ float pS[NREG];
    __shared__ float gS[DIM];
    __shared__ float vgS[DIM], vpS[DIM], bqgS[DIM], bqpS[DIM], bcS[4 * DIM];
    __shared__ int   visited[NREG];
    __shared__ float sS;
    __shared__ int   selS;

    const int t = threadIdx.x;
    const int b = blockIdx.x;

    // ---- stage e_glm into LDS (pitched scalar writes) ----
    const float* eg = egT + (long)b * (NREG * DIM);
    for (int i = t; i < NREG * DIM / 4; i += 256) {
        float4 v = *(const float4*)(eg + i * 4);
        int n = i >> 5, k = (i & 31) * 4;
        En[n][k] = v.x; En[n][k + 1] = v.y; En[n][k + 2] = v.z; En[n][k + 3] = v.w;
    }
    if (t < DIM) {
        cS[t] = 0.f; xh[t] = init_ph[t]; xh[DIM + t] = 0.f;
        visited[t] = 0;
        vgS[t] = glm_v[t]; vpS[t] = ptr_v[t];
        bqgS[t] = glm_bq[t]; bqpS[t] = ptr_bq[t];
    }
    bcS[t] = bcomb[t]; bcS[256 + t] = bcomb[256 + t];
    __syncthreads();

    for (int step = 0; step < TSTEPS; step++) {
        // ---- LSTM gates: g = 2t, 2t+1; k-major coalesced float2 loads ----
        {
            const float* w = WcombT + 2 * t;
            float a0 = 0.f, a1 = 0.f, b0 = 0.f, b1 = 0.f;
#pragma unroll 8
            for (int k = 0; k < 256; k += 2) {
                float2 w0 = *(const float2*)(w + (long)k * 512);
                float2 w1 = *(const float2*)(w + (long)(k + 1) * 512);
                float x0 = xh[k], x1 = xh[k + 1];
                a0 += w0.x * x0; a1 += w0.y * x0;
                b0 += w1.x * x1; b1 += w1.y * x1;
            }
            gates[2 * t]     = a0 + b0 + bcS[2 * t];
            gates[2 * t + 1] = a1 + b1 + bcS[2 * t + 1];
        }
        __syncthreads();
        // ---- LSTM pointwise (i,f,g,o) ----
        if (t < DIM) {
            float ig = fast_sig(gates[t]);
            float fg = fast_sig(gates[DIM + t]);
            float gg = fast_tanh(gates[2 * DIM + t]);
            float og = fast_sig(gates[3 * DIM + t]);
            float cn = fg * cS[t] + ig * gg;
            cS[t] = cn;
            xh[DIM + t] = og * fast_tanh(cn);
        }
        __syncthreads();
        // ---- glimpse query: qpart[h2][o], bias folded into h2==0 ----
        {
            int o = t & 127, h2 = t >> 7;
            const float* w = gWqT + (h2 * 64) * 128 + o;
            float a0 = (h2 == 0) ? bqgS[o] : 0.f, a1 = 0.f;
#pragma unroll 8
            for (int i = 0; i < 64; i += 2) {
                a0 += w[i * 128] * xh[DIM + h2 * 64 + i];
                a1 += w[(i + 1) * 128] * xh[DIM + h2 * 64 + i + 1];
            }
            qpart[h2][o] = a0 + a1;
        }
        __syncthreads();
        // ---- glimpse logits: 2 threads per n, 64 d each ----
        {
            int n = t & 127, h2 = t >> 7;
            float acc = 0.f;
#pragma unroll 4
            for (int j = 0; j < 64; j++) {
                int d = h2 * 64 + j;
                float q = qpart[0][d] + qpart[1][d];
                acc += vgS[d] * fast_tanh(q + En[n][d]);
            }
            lpart[h2][n] = acc;
        }
        __syncthreads();
        // ---- glimpse softmax: single wave (collapse+mask+max+exp+sum) ----
        if (t < 64) {
            float l0 = visited[t]      ? NEGV : (lpart[0][t] + lpart[1][t]);
            float l1 = visited[t + 64] ? NEGV : (lpart[0][t + 64] + lpart[1][t + 64]);
            float m = fmaxf(l0, l1);
            for (int off = 32; off; off >>= 1) m = fmaxf(m, __shfl_xor(m, off, 64));
            float p0 = fast_exp(l0 - m), p1 = fast_exp(l1 - m);
            float s = p0 + p1;
            for (int off = 32; off; off >>= 1) s += __shfl_xor(s, off, 64);
            pS[t] = p0; pS[t + 64] = p1;
            if (t == 0) sS = frcp(s);
        }
        __syncthreads();
        // ---- glimpse combine: gl[d] = (sum_n En[n][d]*p[n]) / s ----
        if (t < DIM) {
            float a0 = 0.f, a1 = 0.f;
#pragma unroll 8
            for (int n = 0; n < NREG; n += 2) {
                a0 += En[n][t] * pS[n];
                a1 += En[n + 1][t] * pS[n + 1];
            }
            gS[t] = (a0 + a1) * sS;
        }
        __syncthreads();
        // ---- pointer query ----
        {
            int o = t & 127, h2 = t >> 7;
            const float* w = pWqT + (h2 * 64) * 128 + o;
            float a0 = (h2 == 0) ? bqpS[o] : 0.f, a1 = 0.f;
#pragma unroll 8
            for (int i = 0; i < 64; i += 2) {
                a0 += w[i * 128] * gS[h2 * 64 + i];
                a1 += w[(i + 1) * 128] * gS[h2 * 64 + i + 1];
            }
            qpart[h2][o] = a0 + a1;
        }
        __syncthreads();
        // ---- pointer logits: Ep streamed from L2, [B,D,N] coalesced over n ----
        {
            int n = t & 127, h2 = t >> 7;
            const float* ep = epT2 + (long)b * (NREG * DIM) + (h2 * 64) * NREG + n;
            float acc = 0.f;
#pragma unroll 8
            for (int j = 0; j < 64; j++) {
                int d = h2 * 64 + j;
                float q = qpart[0][d] + qpart[1][d];
                acc += vpS[d] * fast_tanh(q + ep[j * NREG]);
            }
            lpart[h2][n] = acc;
        }
        __syncthreads();
        // ---- pointer post: collapse + 10*tanh + mask + log_softmax + out + argmax ----
        if (t < 64) {
            float s0 = lpart[0][t] + lpart[1][t];
            float s1 = lpart[0][t + 64] + lpart[1][t + 64];
            float l0 = visited[t]      ? NEGV : 10.f * fast_tanh(s0);
            float l1 = visited[t + 64] ? NEGV : 10.f * fast_tanh(s1);
            float m = fmaxf(l0, l1);
            for (int off = 32; off; off >>= 1) m = fmaxf(m, __shfl_xor(m, off, 64));
            float p0 = fast_exp(l0 - m), p1 = fast_exp(l1 - m);
            float s = p0 + p1;
            for (int off = 32; off; off >>= 1) s += __shfl_xor(s, off, 64);
            float lse = m + fast_log(s);
            float* op = out + ((long)step * BATCH + b) * NREG;
            op[t] = l0 - lse;
            op[t + 64] = l1 - lse;
            // argmax, first-index tie-break
            float v; int idx;
            if (l1 > l0) { v = l1; idx = t + 64; } else { v = l0; idx = t; }
            for (int off = 32; off; off >>= 1) {
                float ov = __shfl_xor(v, off, 64);
                int   oi = __shfl_xor(idx, off, 64);
                if (ov > v || (ov == v && oi < idx)) { v = ov; idx = oi; }
            }
            if (t == 0) selS = idx;
        }
        __syncthreads();
        // ---- visited + next decoder input ----
        if (t < DIM) {
            int sel = selS;
            if (t == 0) visited[sel] = 1;
            xh[t] = emb[((long)sel * BATCH + b) * DIM + t];
        }
        __syncthreads();
    }
}

// ---------------- host launcher ----------------
extern "C" void kernel_launch(void* const* d_in, const int* in_sizes, int n_in,
                              void* d_out, int out_size, void* d_ws, size_t ws_size,
                              hipStream_t stream) {
    const float* data       = (const float*)d_in[0];
    const float* node_embed = (const float*)d_in[1];
    const float* init_ph    = (const float*)d_in[2];
    const float* W1w = (const float*)d_in[3];  const float* W1b = (const float*)d_in[4];
    const float* W2w = (const float*)d_in[5];  const float* W2b = (const float*)d_in[6];
    const float* W3w = (const float*)d_in[7];  const float* W3b = (const float*)d_in[8];
    const float* A1w = (const float*)d_in[9];  const float* A1b = (const float*)d_in[10];
    const float* A2w = (const float*)d_in[11]; const float* A2b = (const float*)d_in[12];
    const float* A3w = (const float*)d_in[13]; const float* A3b = (const float*)d_in[14];
    const float* r1  = (const float*)d_in[15];
    const float* r2  = (const float*)d_in[16];
    const float* r3  = (const float*)d_in[17];
    const float* Wih = (const float*)d_in[18]; const float* Whh = (const float*)d_in[19];
    const float* bih = (const float*)d_in[20]; const float* bhh = (const float*)d_in[21];
    const float* pWq = (const float*)d_in[22]; const float* pbq = (const float*)d_in[23];
    const float* pWr = (const float*)d_in[24]; const float* pbr = (const float*)d_in[25];
    const float* pv  = (const float*)d_in[26];
    const float* gWq = (const float*)d_in[27]; const float* gbq = (const float*)d_in[28];
    const float* gWr = (const float*)d_in[29]; const float* gbr = (const float*)d_in[30];
    const float* gv  = (const float*)d_in[31];
    float* out = (float*)d_out;

    const long SZ = (long)NREG * BATCH * DIM;  // 8388608
    float* ws     = (float*)d_ws;
    float* emb    = ws;
    float* bufA   = ws + SZ;
    float* bufB   = ws + 2 * SZ;
    float* bufC   = ws + 3 * SZ;
    float* meanb  = ws + 4 * SZ;
    float* yagg   = meanb + BATCH * DIM;
    float* WcombT = yagg + BATCH * DIM;         // 131072
    float* bcomb  = WcombT + 256 * 512;         // 512
    float* gWqT   = bcomb + 512;                // 16384
    float* pWqT   = gWqT + DIM * DIM;           // 16384

    const int gemm_grid = (NREG * BATCH) / BM;  // 4096

    k_prep<<<385, 256, 0, stream>>>(Wih, Whh, bih, bhh, gWq, pWq,
                                    WcombT, bcomb, gWqT, pWqT);
    k_embed<<<(int)(SZ / 256), 256, 0, stream>>>(data, node_embed, emb);

    // layer 1: emb -> bufA
    k_mean<<<BATCH, 128, 0, stream>>>(emb, meanb);
    k_agg<<<BATCH, 128, 0, stream>>>(meanb, A1w, A1b, yagg);
    k_gemm<0><<<gemm_grid, 256, 0, stream>>>(emb, W1w, W1b, r1, yagg, bufA);
    // layer 2: bufA -> bufB
    k_mean<<<BATCH, 128, 0, stream>>>(bufA, meanb);
    k_agg<<<BATCH, 128, 0, stream>>>(meanb, A2w, A2b, yagg);
    k_gemm<0><<<gemm_grid, 256, 0, stream>>>(bufA, W2w, W2b, r2, yagg, bufB);
    // layer 3: bufB -> bufC (ctx)
    k_mean<<<BATCH, 128, 0, stream>>>(bufB, meanb);
    k_agg<<<BATCH, 128, 0, stream>>>(meanb, A3w, A3b, yagg);
    k_gemm<0><<<gemm_grid, 256, 0, stream>>>(bufB, W3w, W3b, r3, yagg, bufC);
    // ref projections from ctx: e_ptr -> bufA [B,N,D], e_glm -> bufB [B,N,D]
    k_gemm<1><<<gemm_grid, 256, 0, stream>>>(bufC, pWr, pbr, nullptr, nullptr, bufA);
    k_gemm<1><<<gemm_grid, 256, 0, stream>>>(bufC, gWr, gbr, nullptr, nullptr, bufB);
    // e_ptr [B,N,D] -> [B,D,N] into bufC (ctx no longer needed)
    k_transp<<<BATCH * 16, 256, 0, stream>>>(bufA, bufC);
    // fused 16-step decode
    k_decode<<<BATCH, 256, 0, stream>>>(emb, bufB, bufC, init_ph, WcombT, bcomb,
                                        gWqT, gbq, gv, pWqT, pbq, pv, out);
}

// Round 3
// 448.768 us; speedup vs baseline: 4.3344x; 2.0153x over previous
//
#include <hip/hip_runtime.h>
#include <math.h>

// GPN pointer-network decode, MI355X fp32. N=128, B=512, D=128, T=16.
// R3: full algebraic collapse of the precompute. The context/ref-projection
// chain is affine in data[n,b,:4], so e_glm/e_ptr reduce to rank-4 forms:
//   e[n,b,d] = sum_f data[n,b,f]*Q[f][d] + off[b][d]
// and the glimpse combine reduces to a 4-vector dp = sum_n p[n]*data[n,b,:].
// Decode recomputes e-values on the fly (4 FMA each); no e-tables anywhere.

#define NREG   128
#define BATCH  512
#define DIM    128
#define TSTEPS 16
#define NEGV   (-1e9f)
#define LOG2E  1.4426950408889634f

__device__ __forceinline__ float fexp2(float x) { return __builtin_amdgcn_exp2f(x); }
__device__ __forceinline__ float frcp(float x)  { return __builtin_amdgcn_rcpf(x); }
__device__ __forceinline__ float fast_tanh(float x) {
    return 1.f - 2.f * frcp(1.f + fexp2(2.8853900817779268f * x));
}
__device__ __forceinline__ float fast_sig(float x) {
    return frcp(1.f + fexp2(-LOG2E * x));
}
__device__ __forceinline__ float fast_exp(float x) { return fexp2(LOG2E * x); }
__device__ __forceinline__ float fast_log(float x) {
    return __builtin_amdgcn_logf(x) * 0.6931471805599453f;
}

__device__ __forceinline__ float dot128(const float* __restrict__ wrow,
                                        const float* __restrict__ s) {
    float a0 = 0.f, a1 = 0.f, a2 = 0.f, a3 = 0.f;
#pragma unroll
    for (int k = 0; k < 128; k += 4) {
        a0 += wrow[k] * s[k];     a1 += wrow[k + 1] * s[k + 1];
        a2 += wrow[k + 2] * s[k + 2]; a3 += wrow[k + 3] * s[k + 3];
    }
    return (a0 + a1) + (a2 + a3);
}

// ---------------- K1: misc prep (independent pieces, block-role indexed) ----
// [0,64)   WhhT[k][g] = Whh[g][k]                       (128x512)
// [64,80)  gWqT[i][o] = gWq[o][i]                       (128x128)
// [80,82)  WihNE4[g][f] = sum_d Wih[g][d]*NE[f][d]      (512x4, float4 rows)
// 82       g0[g] = Wih@init ; bc[g] = bih+bhh           (512 each)
// [83,147) A21 = (r2*W2)@(r1*W1)                        (128x128)
// [147,155) md[b][f] = mean_n data[n][b][f]             (512x4)
__global__ __launch_bounds__(256) void k_misc(
    const float* __restrict__ Whh, const float* __restrict__ gWq,
    const float* __restrict__ Wih, const float* __restrict__ NE,
    const float* __restrict__ init_ph,
    const float* __restrict__ bih, const float* __restrict__ bhh,
    const float* __restrict__ W1, const float* __restrict__ W2,
    const float* __restrict__ r1p, const float* __restrict__ r2p,
    const float* __restrict__ data,
    float* __restrict__ WhhT, float* __restrict__ gWqT,
    float* __restrict__ WihNE4, float* __restrict__ g0,
    float* __restrict__ bc, float* __restrict__ A21, float* __restrict__ md)
{
    int blk = blockIdx.x, t = threadIdx.x;
    if (blk < 64) {
        int idx = blk * 256 + t;           // 16384 threads x 4 elems
        int g = idx >> 5, k0 = (idx & 31) * 4;
        float4 v = *(const float4*)(Whh + g * 128 + k0);
        WhhT[(k0 + 0) * 512 + g] = v.x;
        WhhT[(k0 + 1) * 512 + g] = v.y;
        WhhT[(k0 + 2) * 512 + g] = v.z;
        WhhT[(k0 + 3) * 512 + g] = v.w;
    } else if (blk < 80) {
        int idx = (blk - 64) * 256 + t;    // 4096 threads x 4
        int o = idx >> 5, i0 = (idx & 31) * 4;
        float4 v = *(const float4*)(gWq + o * 128 + i0);
        gWqT[(i0 + 0) * 128 + o] = v.x;
        gWqT[(i0 + 1) * 128 + o] = v.y;
        gWqT[(i0 + 2) * 128 + o] = v.z;
        gWqT[(i0 + 3) * 128 + o] = v.w;
    } else if (blk < 82) {
        int g = (blk - 80) * 256 + t;      // 512 threads
        float a0 = 0.f, a1 = 0.f, a2 = 0.f, a3 = 0.f;
        for (int d = 0; d < 128; d += 4) {
            float4 wv = *(const float4*)(Wih + g * 128 + d);
            float4 n0 = *(const float4*)(NE + 0 * 128 + d);
            float4 n1 = *(const float4*)(NE + 1 * 128 + d);
            float4 n2 = *(const float4*)(NE + 2 * 128 + d);
            float4 n3 = *(const float4*)(NE + 3 * 128 + d);
            a0 += wv.x * n0.x + wv.y * n0.y + wv.z * n0.z + wv.w * n0.w;
            a1 += wv.x * n1.x + wv.y * n1.y + wv.z * n1.z + wv.w * n1.w;
            a2 += wv.x * n2.x + wv.y * n2.y + wv.z * n2.z + wv.w * n2.w;
            a3 += wv.x * n3.x + wv.y * n3.y + wv.z * n3.z + wv.w * n3.w;
        }
        *(float4*)(WihNE4 + g * 4) = make_float4(a0, a1, a2, a3);
    } else if (blk == 82) {
        for (int g = t; g < 512; g += 256) {
            float acc = 0.f;
            for (int d = 0; d < 128; d += 4) {
                float4 wv = *(const float4*)(Wih + g * 128 + d);
                float4 iv = *(const float4*)(init_ph + d);
                acc += wv.x * iv.x + wv.y * iv.y + wv.z * iv.z + wv.w * iv.w;
            }
            g0[g] = acc;
            bc[g] = bih[g] + bhh[g];
        }
    } else if (blk < 147) {
        int r = blk - 83;
        int o = r * 2 + (t >> 7), i = t & 127;
        float acc = 0.f;
        for (int k = 0; k < 128; k++) acc += W2[o * 128 + k] * W1[k * 128 + i];
        A21[o * 128 + i] = r1p[0] * r2p[0] * acc;
    } else {
        int idx = (blk - 147) * 256 + t;   // 2048 = B*4
        float acc = 0.f;
        for (int n = 0; n < 128; n++) acc += data[n * 2048 + idx];
        md[idx] = acc * (1.f / 128.f);
    }
}

// ---------------- K2: A3 = r3*W3 @ A21 ----------------
__global__ __launch_bounds__(256) void k_mm2(const float* __restrict__ W3,
                                             const float* __restrict__ A21,
                                             const float* __restrict__ r3p,
                                             float* __restrict__ A3) {
    int o = blockIdx.x * 2 + (threadIdx.x >> 7), i = threadIdx.x & 127;
    float acc = 0.f;
    for (int k = 0; k < 128; k++) acc += W3[o * 128 + k] * A21[k * 128 + i];
    A3[o * 128 + i] = r3p[0] * acc;
}

// ---------------- K3: Mg = gWr@A3 ; Mp = pWr@A3 ----------------
__global__ __launch_bounds__(256) void k_mm3(const float* __restrict__ gWr,
                                             const float* __restrict__ pWr,
                                             const float* __restrict__ A3,
                                             float* __restrict__ Mg,
                                             float* __restrict__ Mp) {
    int blk = blockIdx.x;
    const float* W = (blk < 64) ? gWr : pWr;
    float* Out = (blk < 64) ? Mg : Mp;
    int r = blk & 63;
    int o = r * 2 + (threadIdx.x >> 7), i = threadIdx.x & 127;
    float acc = 0.f;
    for (int k = 0; k < 128; k++) acc += W[o * 128 + k] * A3[k * 128 + i];
    Out[o * 128 + i] = acc;
}

// ---------------- K4: Qg4/Qp4 [o][f] = sum_d NE[f][d]*M[o][d] ----------------
__global__ __launch_bounds__(256) void k_small2(const float* __restrict__ NE,
                                                const float* __restrict__ Mg,
                                                const float* __restrict__ Mp,
                                                float* __restrict__ Qg4,
                                                float* __restrict__ Qp4) {
    const float* M = (blockIdx.x == 0) ? Mg : Mp;
    float* Q = (blockIdx.x == 0) ? Qg4 : Qp4;
    int t = threadIdx.x;
    for (int idx = t; idx < 512; idx += 256) {
        int o = idx >> 2, f = idx & 3;
        float acc = 0.f;
        for (int d = 0; d < 128; d++) acc += NE[f * 128 + d] * M[o * 128 + d];
        Q[idx] = acc;
    }
}

// ---------------- K5: GPQ4[o][f] = sum_i pWq[o][i]*Qg4[i][f] ----------------
__global__ __launch_bounds__(256) void k_small3(const float* __restrict__ pWq,
                                                const float* __restrict__ Qg4,
                                                float* __restrict__ GPQ4) {
    int t = threadIdx.x;
    for (int idx = t; idx < 512; idx += 256) {
        int o = idx >> 2, f = idx & 3;
        float acc = 0.f;
        for (int i = 0; i < 128; i++) acc += pWq[o * 128 + i] * Qg4[i * 4 + f];
        GPQ4[idx] = acc;
    }
}

// ---------------- K6: per-b offset chain (8 b per block) ----------------
// og[b] = gWr@c3 + gbr ; op[b] = pWr@c3 + pbr ; pog[b] = pWq@og + pbq
__global__ __launch_bounds__(256) void k_perb(
    const float* __restrict__ md, const float* __restrict__ NE,
    const float* __restrict__ a1w, const float* __restrict__ a1b,
    const float* __restrict__ a2w, const float* __restrict__ a2b,
    const float* __restrict__ a3w, const float* __restrict__ a3b,
    const float* __restrict__ W1, const float* __restrict__ b1,
    const float* __restrict__ W2, const float* __restrict__ b2,
    const float* __restrict__ W3, const float* __restrict__ b3,
    const float* __restrict__ gWr, const float* __restrict__ gbr,
    const float* __restrict__ pWr, const float* __restrict__ pbr,
    const float* __restrict__ pWq, const float* __restrict__ pbq,
    const float* __restrict__ r1p, const float* __restrict__ r2p,
    const float* __restrict__ r3p,
    float* __restrict__ og, float* __restrict__ op, float* __restrict__ pog)
{
    __shared__ float Ws[128 * 129];
    __shared__ float me[1024], Cv[1024], Mv[1024], Tv[1024], C2[1024], M2[1024];
    __shared__ float NEs[512], mdS[32];
    const int t = threadIdx.x;
    const int b0 = blockIdx.x * 8;
    const float r1 = r1p[0], r2 = r2p[0], r3 = r3p[0];

#define STAGE_W(Wptr)                                                          \
    for (int i = t * 4; i < 16384; i += 1024) {                                \
        float4 v = *(const float4*)((Wptr) + i);                               \
        int oo = i >> 7, kk = i & 127;                                         \
        float* p = &Ws[oo * 129 + kk];                                         \
        p[0] = v.x; p[1] = v.y; p[2] = v.z; p[3] = v.w;                        \
    }

    if (t < 32) mdS[t] = md[b0 * 4 + t];
    for (int i = t; i < 512; i += 256) NEs[i] = NE[i];
    __syncthreads();
    // me[j][d] = sum_f mdS[j][f]*NEs[f][d]
    for (int idx = t; idx < 1024; idx += 256) {
        int j = idx >> 7, d = idx & 127;
        me[idx] = mdS[j * 4 + 0] * NEs[d] + mdS[j * 4 + 1] * NEs[128 + d] +
                  mdS[j * 4 + 2] * NEs[256 + d] + mdS[j * 4 + 3] * NEs[384 + d];
    }
    STAGE_W(a1w);
    __syncthreads();
    {   // Tv = g1 = (1-r1)*relu(agg1@me + a1b)
        int o = t & 127, jg = t >> 7;
        for (int jj = 0; jj < 4; jj++) {
            int j = jg * 4 + jj;
            float acc = dot128(&Ws[o * 129], &me[j * 128]);
            Tv[j * 128 + o] = (1.f - r1) * fmaxf(acc + a1b[o], 0.f);
        }
    }
    __syncthreads();
    STAGE_W(W1);
    for (int idx = t; idx < 1024; idx += 256) Cv[idx] = r1 * b1[idx & 127] + Tv[idx];
    __syncthreads();
    {   // Mv = mc1 = r1*(W1@me + b1) + g1
        int o = t & 127, jg = t >> 7;
        for (int jj = 0; jj < 4; jj++) {
            int j = jg * 4 + jj;
            float acc = dot128(&Ws[o * 129], &me[j * 128]);
            Mv[j * 128 + o] = r1 * (acc + b1[o]) + Tv[j * 128 + o];
        }
    }
    __syncthreads();
    STAGE_W(a2w);
    __syncthreads();
    {   // Tv = g2
        int o = t & 127, jg = t >> 7;
        for (int jj = 0; jj < 4; jj++) {
            int j = jg * 4 + jj;
            float acc = dot128(&Ws[o * 129], &Mv[j * 128]);
            Tv[j * 128 + o] = (1.f - r2) * fmaxf(acc + a2b[o], 0.f);
        }
    }
    __syncthreads();
    STAGE_W(W2);
    __syncthreads();
    {   // C2 = r2*(W2@Cv+b2)+g2 ; M2 = r2*(W2@Mv+b2)+g2
        int o = t & 127, jg = t >> 7;
        for (int jj = 0; jj < 4; jj++) {
            int j = jg * 4 + jj;
            float ac = dot128(&Ws[o * 129], &Cv[j * 128]);
            float am = dot128(&Ws[o * 129], &Mv[j * 128]);
            C2[j * 128 + o] = r2 * (ac + b2[o]) + Tv[j * 128 + o];
            M2[j * 128 + o] = r2 * (am + b2[o]) + Tv[j * 128 + o];
        }
    }
    __syncthreads();
    STAGE_W(a3w);
    __syncthreads();
    {   // Tv = g3
        int o = t & 127, jg = t >> 7;
        for (int jj = 0; jj < 4; jj++) {
            int j = jg * 4 + jj;
            float acc = dot128(&Ws[o * 129], &M2[j * 128]);
            Tv[j * 128 + o] = (1.f - r3) * fmaxf(acc + a3b[o], 0.f);
        }
    }
    __syncthreads();
    STAGE_W(W3);
    __syncthreads();
    {   // Cv = c3 = r3*(W3@C2 + b3) + g3
        int o = t & 127, jg = t >> 7;
        for (int jj = 0; jj < 4; jj++) {
            int j = jg * 4 + jj;
            float acc = dot128(&Ws[o * 129], &C2[j * 128]);
            Cv[j * 128 + o] = r3 * (acc + b3[o]) + Tv[j * 128 + o];
        }
    }
    __syncthreads();
    STAGE_W(gWr);
    __syncthreads();
    {   // Mv = og = gWr@c3 + gbr  (kept in LDS for pog)
        int o = t & 127, jg = t >> 7;
        for (int jj = 0; jj < 4; jj++) {
            int j = jg * 4 + jj;
            float acc = dot128(&Ws[o * 129], &Cv[j * 128]) + gbr[o];
            Mv[j * 128 + o] = acc;
            og[(long)(b0 + j) * 128 + o] = acc;
        }
    }
    __syncthreads();
    STAGE_W(pWr);
    __syncthreads();
    {   // op = pWr@c3 + pbr
        int o = t & 127, jg = t >> 7;
        for (int jj = 0; jj < 4; jj++) {
            int j = jg * 4 + jj;
            op[(long)(b0 + j) * 128 + o] = dot128(&Ws[o * 129], &Cv[j * 128]) + pbr[o];
        }
    }
    __syncthreads();
    STAGE_W(pWq);
    __syncthreads();
    {   // pog = pWq@og + pbq
        int o = t & 127, jg = t >> 7;
        for (int jj = 0; jj < 4; jj++) {
            int j = jg * 4 + jj;
            pog[(long)(b0 + j) * 128 + o] = dot128(&Ws[o * 129], &Mv[j * 128]) + pbq[o];
        }
    }
#undef STAGE_W
}

// ---------------- K7: persistent decode, 1 block / batch element ----------------
__global__ __launch_bounds__(256, 2) void k_decode(
    const float* __restrict__ dataIn,   // [N,B,4]
    const float* __restrict__ WhhT,     // [128][512]
    const float* __restrict__ gWqT,     // [128][128]
    const float* __restrict__ WihNE4,   // [512][4]
    const float* __restrict__ g0,       // [512] Wih@init
    const float* __restrict__ bc,       // [512] bih+bhh
    const float* __restrict__ Qg4, const float* __restrict__ Qp4,
    const float* __restrict__ GPQ4,     // [128][4] each
    const float* __restrict__ ogG, const float* __restrict__ opG,
    const float* __restrict__ pogG,     // [B][128] each
    const float* __restrict__ gbq, const float* __restrict__ vgG,
    const float* __restrict__ vpG,
    float* __restrict__ out)            // [T,B,N]
{
    __shared__ float4 dataS[128];
    __shared__ float4 WihS[512];
    __shared__ float4 QgS[128], QpS[128], GPQS[128];
    __shared__ float g0S[512], bcS[512], gatesS[512];
    __shared__ float ogS[128], opS[128], pogS[128], gbqS[128], vgS[128], vpS[128];
    __shared__ float hS[128], cS[128], qpart[2][128], lpart[2][128], qpS[128];
    __shared__ int visitedS[128];
    __shared__ int selS;

    const int t = threadIdx.x;
    const int b = blockIdx.x;

    if (t < 128) {
        dataS[t] = *(const float4*)(dataIn + ((long)t * 512 + b) * 4);
        QgS[t]  = *(const float4*)(Qg4 + t * 4);
        QpS[t]  = *(const float4*)(Qp4 + t * 4);
        GPQS[t] = *(const float4*)(GPQ4 + t * 4);
        ogS[t]  = ogG[(long)b * 128 + t];
        opS[t]  = opG[(long)b * 128 + t];
        pogS[t] = pogG[(long)b * 128 + t];
        gbqS[t] = gbq[t];
        vgS[t]  = vgG[t];
        vpS[t]  = vpG[t];
        hS[t] = 0.f; cS[t] = 0.f;
        visitedS[t] = 0;
    }
    WihS[t] = *(const float4*)(WihNE4 + t * 4);
    WihS[t + 256] = *(const float4*)(WihNE4 + (t + 256) * 4);
    g0S[t] = g0[t]; g0S[t + 256] = g0[t + 256];
    bcS[t] = bc[t]; bcS[t + 256] = bc[t + 256];
    __syncthreads();

    for (int step = 0; step < TSTEPS; step++) {
        // ---- gates: ih-part via rank-4 combo, hh-part streamed from L2 ----
        {
            float accA, accB;
            if (step == 0) {
                accA = g0S[2 * t]; accB = g0S[2 * t + 1];
            } else {
                float4 xd = dataS[selS];
                float4 wA = WihS[2 * t], wB = WihS[2 * t + 1];
                accA = xd.x * wA.x + xd.y * wA.y + xd.z * wA.z + xd.w * wA.w;
                accB = xd.x * wB.x + xd.y * wB.y + xd.z * wB.z + xd.w * wB.w;
            }
            accA += bcS[2 * t]; accB += bcS[2 * t + 1];
            const float* w = WhhT + 2 * t;
            float a0 = 0.f, a1 = 0.f, b0_ = 0.f, b1_ = 0.f;
#pragma unroll 8
            for (int k = 0; k < 128; k += 2) {
                float2 w0 = *(const float2*)(w + (long)k * 512);
                float2 w1 = *(const float2*)(w + (long)(k + 1) * 512);
                float h0 = hS[k], h1 = hS[k + 1];
                a0 += w0.x * h0; a1 += w0.y * h0;
                b0_ += w1.x * h1; b1_ += w1.y * h1;
            }
            gatesS[2 * t] = accA + a0 + b0_;
            gatesS[2 * t + 1] = accB + a1 + b1_;
        }
        __syncthreads();
        // ---- LSTM pointwise (i,f,g,o) ----
        if (t < 128) {
            float ig = fast_sig(gatesS[t]);
            float fg = fast_sig(gatesS[128 + t]);
            float gg = fast_tanh(gatesS[256 + t]);
            float og_ = fast_sig(gatesS[384 + t]);
            float cn = fg * cS[t] + ig * gg;
            cS[t] = cn;
            hS[t] = og_ * fast_tanh(cn);
        }
        __syncthreads();
        // ---- glimpse query: q[o] = gWq@h + gbq, split over 2 half-dots ----
        {
            int o = t & 127, h2 = t >> 7;
            const float* w = gWqT + (h2 * 64) * 128 + o;
            float a0 = (h2 == 0) ? gbqS[o] : 0.f, a1 = 0.f;
#pragma unroll 8
            for (int i = 0; i < 64; i += 2) {
                a0 += w[i * 128] * hS[h2 * 64 + i];
                a1 += w[(i + 1) * 128] * hS[h2 * 64 + i + 1];
            }
            qpart[h2][o] = a0 + a1;
        }
        __syncthreads();
        // ---- glimpse logits: Eg recomputed as rank-4 combo ----
        {
            int n = t & 127, h2 = t >> 7;
            float4 dn = dataS[n];
            float acc = 0.f;
#pragma unroll 4
            for (int j = 0; j < 64; j++) {
                int d = h2 * 64 + j;
                float4 qg = QgS[d];
                float eg = dn.x * qg.x + dn.y * qg.y + dn.z * qg.z + dn.w * qg.w
                         + ogS[d];
                float q = qpart[0][d] + qpart[1][d];
                acc += vgS[d] * fast_tanh(q + eg);
            }
            lpart[h2][n] = acc;
        }
        __syncthreads();
        // ---- glimpse softmax + dp reduce + pointer query (single wave) ----
        if (t < 64) {
            float l0 = visitedS[t]      ? NEGV : lpart[0][t] + lpart[1][t];
            float l1 = visitedS[t + 64] ? NEGV : lpart[0][t + 64] + lpart[1][t + 64];
            float m = fmaxf(l0, l1);
            for (int off = 32; off; off >>= 1) m = fmaxf(m, __shfl_xor(m, off, 64));
            float p0 = fast_exp(l0 - m), p1 = fast_exp(l1 - m);
            float s = p0 + p1;
            float4 d0 = dataS[t], d1 = dataS[t + 64];
            float q0 = p0 * d0.x + p1 * d1.x;
            float q1 = p0 * d0.y + p1 * d1.y;
            float q2 = p0 * d0.z + p1 * d1.z;
            float q3 = p0 * d0.w + p1 * d1.w;
            for (int off = 32; off; off >>= 1) {
                s  += __shfl_xor(s, off, 64);
                q0 += __shfl_xor(q0, off, 64);
                q1 += __shfl_xor(q1, off, 64);
                q2 += __shfl_xor(q2, off, 64);
                q3 += __shfl_xor(q3, off, 64);
            }
            float inv = frcp(s);
            q0 *= inv; q1 *= inv; q2 *= inv; q3 *= inv;
            float4 gA = GPQS[t];
            qpS[t] = q0 * gA.x + q1 * gA.y + q2 * gA.z + q3 * gA.w + pogS[t];
            float4 gB = GPQS[t + 64];
            qpS[t + 64] = q0 * gB.x + q1 * gB.y + q2 * gB.z + q3 * gB.w + pogS[t + 64];
        }
        __syncthreads();
        // ---- pointer logits: Ep recomputed as rank-4 combo ----
        {
            int n = t & 127, h2 = t >> 7;
            float4 dn = dataS[n];
            float acc = 0.f;
#pragma unroll 4
            for (int j = 0; j < 64; j++) {
                int d = h2 * 64 + j;
                float4 qp = QpS[d];
                float ep = dn.x * qp.x + dn.y * qp.y + dn.z * qp.z + dn.w * qp.w
                         + opS[d];
                acc += vpS[d] * fast_tanh(qpS[d] + ep);
            }
            lpart[h2][n] = acc;
        }
        __syncthreads();
        // ---- pointer post: 10*tanh, mask, log_softmax, out, argmax (1 wave) ----
        if (t < 64) {
            float s0 = lpart[0][t] + lpart[1][t];
            float s1 = lpart[0][t + 64] + lpart[1][t + 64];
            float l0 = visitedS[t]      ? NEGV : 10.f * fast_tanh(s0);
            float l1 = visitedS[t + 64] ? NEGV : 10.f * fast_tanh(s1);
            float m = fmaxf(l0, l1);
            for (int off = 32; off; off >>= 1) m = fmaxf(m, __shfl_xor(m, off, 64));
            float p0 = fast_exp(l0 - m), p1 = fast_exp(l1 - m);
            float s = p0 + p1;
            for (int off = 32; off; off >>= 1) s += __shfl_xor(s, off, 64);
            float lse = m + fast_log(s);
            float* outp = out + ((long)step * BATCH + b) * NREG;
            outp[t] = l0 - lse;
            outp[t + 64] = l1 - lse;
            float v; int idx;
            if (l1 > l0) { v = l1; idx = t + 64; } else { v = l0; idx = t; }
            for (int off = 32; off; off >>= 1) {
                float ov = __shfl_xor(v, off, 64);
                int   oi = __shfl_xor(idx, off, 64);
                if (ov > v || (ov == v && oi < idx)) { v = ov; idx = oi; }
            }
            if (t == 0) { selS = idx; visitedS[idx] = 1; }
        }
        __syncthreads();
    }
}

// ---------------- host launcher ----------------
extern "C" void kernel_launch(void* const* d_in, const int* in_sizes, int n_in,
                              void* d_out, int out_size, void* d_ws, size_t ws_size,
                              hipStream_t stream) {
    const float* data = (const float*)d_in[0];
    const float* NE   = (const float*)d_in[1];
    const float* init = (const float*)d_in[2];
    const float* W1w = (const float*)d_in[3];  const float* W1b = (const float*)d_in[4];
    const float* W2w = (const float*)d_in[5];  const float* W2b = (const float*)d_in[6];
    const float* W3w = (const float*)d_in[7];  const float* W3b = (const float*)d_in[8];
    const float* A1w = (const float*)d_in[9];  const float* A1b = (const float*)d_in[10];
    const float* A2w = (const float*)d_in[11]; const float* A2b = (const float*)d_in[12];
    const float* A3w = (const float*)d_in[13]; const float* A3b = (const float*)d_in[14];
    const float* r1  = (const float*)d_in[15];
    const float* r2  = (const float*)d_in[16];
    const float* r3  = (const float*)d_in[17];
    const float* Wih = (const float*)d_in[18]; const float* Whh = (const float*)d_in[19];
    const float* bih = (const float*)d_in[20]; const float* bhh = (const float*)d_in[21];
    const float* pWq = (const float*)d_in[22]; const float* pbq = (const float*)d_in[23];
    const float* pWr = (const float*)d_in[24]; const float* pbr = (const float*)d_in[25];
    const float* pv  = (const float*)d_in[26];
    const float* gWq = (const float*)d_in[27]; const float* gbq = (const float*)d_in[28];
    const float* gWr = (const float*)d_in[29]; const float* gbr = (const float*)d_in[30];
    const float* gv  = (const float*)d_in[31];
    float* out = (float*)d_out;

    float* ws     = (float*)d_ws;
    float* WhhT   = ws;                    // 65536
    float* gWqT   = WhhT + 65536;          // 16384
    float* WihNE4 = gWqT + 16384;          // 2048
    float* g0     = WihNE4 + 2048;         // 512
    float* bc     = g0 + 512;              // 512
    float* A21    = bc + 512;              // 16384
    float* A3     = A21 + 16384;           // 16384
    float* Mg     = A3 + 16384;            // 16384
    float* Mp     = Mg + 16384;            // 16384
    float* Qg4    = Mp + 16384;            // 512
    float* Qp4    = Qg4 + 512;             // 512
    float* GPQ4   = Qp4 + 512;             // 512
    float* md     = GPQ4 + 512;            // 2048
    float* og     = md + 2048;             // 65536
    float* op     = og + 65536;            // 65536
    float* pog    = op + 65536;            // 65536

    k_misc<<<155, 256, 0, stream>>>(Whh, gWq, Wih, NE, init, bih, bhh,
                                    W1w, W2w, r1, r2, data,
                                    WhhT, gWqT, WihNE4, g0, bc, A21, md);
    k_mm2<<<64, 256, 0, stream>>>(W3w, A21, r3, A3);
    k_mm3<<<128, 256, 0, stream>>>(gWr, pWr, A3, Mg, Mp);
    k_small2<<<2, 256, 0, stream>>>(NE, Mg, Mp, Qg4, Qp4);
    k_small3<<<1, 256, 0, stream>>>(pWq, Qg4, GPQ4);
    k_perb<<<64, 256, 0, stream>>>(md, NE, A1w, A1b, A2w, A2b, A3w, A3b,
                                   W1w, W1b, W2w, W2b, W3w, W3b,
                                   gWr, gbr, pWr, pbr, pWq, pbq,
                                   r1, r2, r3, og, op, pog);
    k_decode<<<BATCH, 256, 0, stream>>>(data, WhhT, gWqT, WihNE4, g0, bc,
                                        Qg4, Qp4, GPQ4, og, op, pog,
                                        gbq, gv, pv, out);
}

// Round 4
// 400.733 us; speedup vs baseline: 4.8540x; 1.1199x over previous
//
#include <hip/hip_runtime.h>
#include <math.h>

// GPN pointer-network decode, MI355X fp32. N=128, B=512, D=128, T=16.
// R4: (1) whole prep in ONE kernel (role-blocks; Q-chain right-multiplied by
// NE^T is 128x4 per stage -> single block), (2) decode 512-thread blocks
// (16 waves/CU), (3) tanh loops prescaled by C=2*log2e with -2v folded into
// the accumulator FMA; glimpse sum-const dropped (softmax shift-invariant),
// (4) Whh/gWq panel-packed k-major float4 for coalesced matvec streams.

#define NREG   128
#define BATCH  512
#define DIM    128
#define TSTEPS 16
#define NEGV   (-1e9f)
#define LOG2E  1.4426950408889634f
#define CT     2.8853900817779268f   // 2*log2(e)

__device__ __forceinline__ float fexp2(float x) { return __builtin_amdgcn_exp2f(x); }
__device__ __forceinline__ float frcp(float x)  { return __builtin_amdgcn_rcpf(x); }
__device__ __forceinline__ float fast_tanh(float x) {
    return 1.f - 2.f * frcp(1.f + fexp2(CT * x));
}
__device__ __forceinline__ float fast_sig(float x) {
    return frcp(1.f + fexp2(-LOG2E * x));
}
__device__ __forceinline__ float fast_exp(float x) { return fexp2(LOG2E * x); }
__device__ __forceinline__ float fast_log(float x) {
    return __builtin_amdgcn_logf(x) * 0.6931471805599453f;
}

__device__ __forceinline__ float dot128(const float* __restrict__ wrow,
                                        const float* __restrict__ s) {
    float a0 = 0.f, a1 = 0.f, a2 = 0.f, a3 = 0.f;
#pragma unroll
    for (int k = 0; k < 128; k += 4) {
        a0 += wrow[k] * s[k];         a1 += wrow[k + 1] * s[k + 1];
        a2 += wrow[k + 2] * s[k + 2]; a3 += wrow[k + 3] * s[k + 3];
    }
    return (a0 + a1) + (a2 + a3);
}

// ---------------- K1: ALL prep in one launch (role-indexed blocks) ----------
// [0,64)   WhhP[kb][g] = float4(Whh[g][4kb..4kb+3])        (32x512 float4)
// [64,80)  gWqP[ib][o] = float4(gWq[o][4ib..4ib+3])        (32x128 float4)
// [80,82)  WihNE4[g][f] = sum_d Wih[g][d]*NE[f][d]         (512x4)
// 82       g0 = Wih@init ; bc = bih+bhh ; sumvp = sum(pv)
// 83       Q-chain (single block): U3 = (r3W3)(r2W2)(r1W1)@NE^T (128x4);
//          Qgc = CT*gWr@U3 ; Qpc = CT*pWr@U3 ; GPQ = pWq@(gWr@U3)
// [84,148) per-b offset chain, 8 b per block: og/op/pog    (B x 128 each)
__global__ __launch_bounds__(256) void k_misc(
    const float* __restrict__ Whh, const float* __restrict__ gWq,
    const float* __restrict__ Wih, const float* __restrict__ NE,
    const float* __restrict__ init_ph,
    const float* __restrict__ bih, const float* __restrict__ bhh,
    const float* __restrict__ W1, const float* __restrict__ b1,
    const float* __restrict__ W2, const float* __restrict__ b2,
    const float* __restrict__ W3, const float* __restrict__ b3,
    const float* __restrict__ a1w, const float* __restrict__ a1b,
    const float* __restrict__ a2w, const float* __restrict__ a2b,
    const float* __restrict__ a3w, const float* __restrict__ a3b,
    const float* __restrict__ gWr, const float* __restrict__ gbr,
    const float* __restrict__ pWr, const float* __restrict__ pbr,
    const float* __restrict__ pWq, const float* __restrict__ pbq,
    const float* __restrict__ r1p, const float* __restrict__ r2p,
    const float* __restrict__ r3p,
    const float* __restrict__ pv, const float* __restrict__ data,
    float* __restrict__ WhhP, float* __restrict__ gWqP,
    float* __restrict__ WihNE4, float* __restrict__ g0,
    float* __restrict__ bc, float* __restrict__ sumvp,
    float* __restrict__ Qgc, float* __restrict__ Qpc, float* __restrict__ GPQ,
    float* __restrict__ og, float* __restrict__ op, float* __restrict__ pog)
{
    __shared__ float Ws[128 * 129];
    __shared__ float me[1024], Cv[1024], Mv[1024], Tv[1024], C2[1024], M2[1024];
    __shared__ float NEs[512], mdS[32];
    __shared__ float4 Uc[128], Vc[128], Qgu[128];

    const int blk = blockIdx.x, t = threadIdx.x;

    if (blk < 64) {
        int idx = blk * 256 + t;            // 16384: kb = idx>>9, g = idx&511
        int kb = idx >> 9, g = idx & 511;
        float4 v = *(const float4*)(Whh + g * 128 + kb * 4);
        ((float4*)WhhP)[kb * 512 + g] = v;
    } else if (blk < 80) {
        int idx = (blk - 64) * 256 + t;     // 4096: ib = idx>>7, o = idx&127
        int ib = idx >> 7, o = idx & 127;
        float4 v = *(const float4*)(gWq + o * 128 + ib * 4);
        ((float4*)gWqP)[ib * 128 + o] = v;
    } else if (blk < 82) {
        int g = (blk - 80) * 256 + t;
        float a0 = 0.f, a1 = 0.f, a2 = 0.f, a3 = 0.f;
        for (int d = 0; d < 128; d += 4) {
            float4 wv = *(const float4*)(Wih + g * 128 + d);
            float4 n0 = *(const float4*)(NE + 0 * 128 + d);
            float4 n1 = *(const float4*)(NE + 1 * 128 + d);
            float4 n2 = *(const float4*)(NE + 2 * 128 + d);
            float4 n3 = *(const float4*)(NE + 3 * 128 + d);
            a0 += wv.x * n0.x + wv.y * n0.y + wv.z * n0.z + wv.w * n0.w;
            a1 += wv.x * n1.x + wv.y * n1.y + wv.z * n1.z + wv.w * n1.w;
            a2 += wv.x * n2.x + wv.y * n2.y + wv.z * n2.z + wv.w * n2.w;
            a3 += wv.x * n3.x + wv.y * n3.y + wv.z * n3.z + wv.w * n3.w;
        }
        *(float4*)(WihNE4 + g * 4) = make_float4(a0, a1, a2, a3);
    } else if (blk == 82) {
        for (int g = t; g < 512; g += 256) {
            float acc = 0.f;
            for (int d = 0; d < 128; d += 4) {
                float4 wv = *(const float4*)(Wih + g * 128 + d);
                float4 iv = *(const float4*)(init_ph + d);
                acc += wv.x * iv.x + wv.y * iv.y + wv.z * iv.z + wv.w * iv.w;
            }
            g0[g] = acc;
            bc[g] = bih[g] + bhh[g];
        }
        if (t < 64) {
            float sv = pv[t] + pv[t + 64];
            for (int off = 32; off; off >>= 1) sv += __shfl_xor(sv, off, 64);
            if (t == 0) sumvp[0] = sv;
        }
    } else if (blk == 83) {
        // Q-chain, one block. Stage: DST[o] = sc * sum_k W[o][k]*SRC[k] (128x4)
        if (t < 128)
            Uc[t] = make_float4(NE[t], NE[128 + t], NE[256 + t], NE[384 + t]);
        __syncthreads();
#define CH_STAGE(Wp, SRC, DST, SC)                                             \
        if (t < 128) {                                                         \
            const float* wr = (Wp) + t * 128;                                  \
            float ax = 0.f, ay = 0.f, az = 0.f, aw = 0.f;                      \
            _Pragma("unroll 8")                                                \
            for (int k = 0; k < 128; k++) {                                    \
                float w = wr[k]; float4 u = SRC[k];                            \
                ax += w * u.x; ay += w * u.y; az += w * u.z; aw += w * u.w;    \
            }                                                                  \
            float sc = (SC);                                                   \
            DST[t] = make_float4(sc * ax, sc * ay, sc * az, sc * aw);          \
        }                                                                      \
        __syncthreads();
        CH_STAGE(W1, Uc, Vc, r1p[0])     // Vc = U1
        CH_STAGE(W2, Vc, Uc, r2p[0])     // Uc = U2
        CH_STAGE(W3, Uc, Vc, r3p[0])     // Vc = U3
        CH_STAGE(gWr, Vc, Qgu, 1.f)      // Qgu = Qg (unscaled)
        CH_STAGE(pWr, Vc, Uc, 1.f)       // Uc = Qp
        CH_STAGE(pWq, Qgu, Vc, 1.f)      // Vc = GPQ
        if (t < 128) {
            float4 qg = Qgu[t], qp = Uc[t];
            ((float4*)Qgc)[t] = make_float4(CT * qg.x, CT * qg.y, CT * qg.z, CT * qg.w);
            ((float4*)Qpc)[t] = make_float4(CT * qp.x, CT * qp.y, CT * qp.z, CT * qp.w);
            ((float4*)GPQ)[t] = Vc[t];
        }
#undef CH_STAGE
    } else {
        // ---- per-b offset chain, 8 b per block ----
        const int b0 = (blk - 84) * 8;
        const float r1 = r1p[0], r2 = r2p[0], r3 = r3p[0];
#define STAGE_W(Wptr)                                                          \
        for (int i = t * 4; i < 16384; i += 1024) {                            \
            float4 v = *(const float4*)((Wptr) + i);                           \
            int oo = i >> 7, kk = i & 127;                                     \
            float* p = &Ws[oo * 129 + kk];                                     \
            p[0] = v.x; p[1] = v.y; p[2] = v.z; p[3] = v.w;                    \
        }
        if (t < 32) {
            int j = t >> 2, f = t & 3;
            float acc = 0.f;
            for (int n = 0; n < 128; n++) acc += data[n * 2048 + (b0 + j) * 4 + f];
            mdS[t] = acc * (1.f / 128.f);
        }
        for (int i = t; i < 512; i += 256) NEs[i] = NE[i];
        __syncthreads();
        for (int idx = t; idx < 1024; idx += 256) {
            int j = idx >> 7, d = idx & 127;
            me[idx] = mdS[j * 4 + 0] * NEs[d] + mdS[j * 4 + 1] * NEs[128 + d] +
                      mdS[j * 4 + 2] * NEs[256 + d] + mdS[j * 4 + 3] * NEs[384 + d];
        }
        STAGE_W(a1w);
        __syncthreads();
        {   // Tv = g1 = (1-r1)*relu(agg1@me + a1b)
            int o = t & 127, jg = t >> 7;
            for (int jj = 0; jj < 4; jj++) {
                int j = jg * 4 + jj;
                float acc = dot128(&Ws[o * 129], &me[j * 128]);
                Tv[j * 128 + o] = (1.f - r1) * fmaxf(acc + a1b[o], 0.f);
            }
        }
        __syncthreads();
        STAGE_W(W1);
        for (int idx = t; idx < 1024; idx += 256) Cv[idx] = r1 * b1[idx & 127] + Tv[idx];
        __syncthreads();
        {   // Mv = r1*(W1@me + b1) + g1
            int o = t & 127, jg = t >> 7;
            for (int jj = 0; jj < 4; jj++) {
                int j = jg * 4 + jj;
                float acc = dot128(&Ws[o * 129], &me[j * 128]);
                Mv[j * 128 + o] = r1 * (acc + b1[o]) + Tv[j * 128 + o];
            }
        }
        __syncthreads();
        STAGE_W(a2w);
        __syncthreads();
        {   // Tv = g2
            int o = t & 127, jg = t >> 7;
            for (int jj = 0; jj < 4; jj++) {
                int j = jg * 4 + jj;
                float acc = dot128(&Ws[o * 129], &Mv[j * 128]);
                Tv[j * 128 + o] = (1.f - r2) * fmaxf(acc + a2b[o], 0.f);
            }
        }
        __syncthreads();
        STAGE_W(W2);
        __syncthreads();
        {   // C2 = r2*(W2@Cv+b2)+g2 ; M2 = r2*(W2@Mv+b2)+g2
            int o = t & 127, jg = t >> 7;
            for (int jj = 0; jj < 4; jj++) {
                int j = jg * 4 + jj;
                float ac = dot128(&Ws[o * 129], &Cv[j * 128]);
                float am = dot128(&Ws[o * 129], &Mv[j * 128]);
                C2[j * 128 + o] = r2 * (ac + b2[o]) + Tv[j * 128 + o];
                M2[j * 128 + o] = r2 * (am + b2[o]) + Tv[j * 128 + o];
            }
        }
        __syncthreads();
        STAGE_W(a3w);
        __syncthreads();
        {   // Tv = g3
            int o = t & 127, jg = t >> 7;
            for (int jj = 0; jj < 4; jj++) {
                int j = jg * 4 + jj;
                float acc = dot128(&Ws[o * 129], &M2[j * 128]);
                Tv[j * 128 + o] = (1.f - r3) * fmaxf(acc + a3b[o], 0.f);
            }
        }
        __syncthreads();
        STAGE_W(W3);
        __syncthreads();
        {   // Cv = c3 = r3*(W3@C2 + b3) + g3
            int o = t & 127, jg = t >> 7;
            for (int jj = 0; jj < 4; jj++) {
                int j = jg * 4 + jj;
                float acc = dot128(&Ws[o * 129], &C2[j * 128]);
                Cv[j * 128 + o] = r3 * (acc + b3[o]) + Tv[j * 128 + o];
            }
        }
        __syncthreads();
        STAGE_W(gWr);
        __syncthreads();
        {   // Mv = og = gWr@c3 + gbr (kept for pog)
            int o = t & 127, jg = t >> 7;
            for (int jj = 0; jj < 4; jj++) {
                int j = jg * 4 + jj;
                float acc = dot128(&Ws[o * 129], &Cv[j * 128]) + gbr[o];
                Mv[j * 128 + o] = acc;
                og[(long)(b0 + j) * 128 + o] = acc;
            }
        }
        __syncthreads();
        STAGE_W(pWr);
        __syncthreads();
        {   // op = pWr@c3 + pbr
            int o = t & 127, jg = t >> 7;
            for (int jj = 0; jj < 4; jj++) {
                int j = jg * 4 + jj;
                op[(long)(b0 + j) * 128 + o] = dot128(&Ws[o * 129], &Cv[j * 128]) + pbr[o];
            }
        }
        __syncthreads();
        STAGE_W(pWq);
        __syncthreads();
        {   // pog = pWq@og + pbq
            int o = t & 127, jg = t >> 7;
            for (int jj = 0; jj < 4; jj++) {
                int j = jg * 4 + jj;
                pog[(long)(b0 + j) * 128 + o] = dot128(&Ws[o * 129], &Mv[j * 128]) + pbq[o];
            }
        }
#undef STAGE_W
    }
}

// ---------------- K2: persistent decode, 512 threads / block, 1 block / b ----
__global__ __launch_bounds__(512, 4) void k_decode(
    const float* __restrict__ dataIn,   // [N,B,4]
    const float* __restrict__ WhhP,     // [32][512] float4 panels
    const float* __restrict__ gWqP,     // [32][128] float4 panels
    const float* __restrict__ WihNE4,   // [512][4]
    const float* __restrict__ g0,       // [512]
    const float* __restrict__ bc,       // [512]
    const float* __restrict__ Qgc, const float* __restrict__ Qpc,
    const float* __restrict__ GPQ,      // [128][4] each (Qgc/Qpc pre-scaled by CT)
    const float* __restrict__ ogG, const float* __restrict__ opG,
    const float* __restrict__ pogG,     // [B][128] each
    const float* __restrict__ gbq, const float* __restrict__ vgG,
    const float* __restrict__ vpG, const float* __restrict__ sumvpG,
    float* __restrict__ out)            // [T,B,N]
{
    __shared__ float4 dataS[128];
    __shared__ float4 WihS[512];
    __shared__ float4 QgcS[128], QpcS[128], GPQS[128];
    __shared__ float g0S[512], bcS[512], gatesS[512];
    __shared__ float ogS[128], opS[128], pogS[128];
    __shared__ float gbqS[128], vg2S[128], vp2S[128];
    __shared__ float hS[128], cS[128], qeS[128], qepS[128];
    __shared__ float lpart[4][128];
    __shared__ int   visitedS[128];
    __shared__ int   selS;
    __shared__ float sumvpS;

    const int t = threadIdx.x;
    const int b = blockIdx.x;

    if (t < 128) {
        dataS[t] = *(const float4*)(dataIn + ((long)t * 512 + b) * 4);
        QgcS[t]  = ((const float4*)Qgc)[t];
        QpcS[t]  = ((const float4*)Qpc)[t];
        GPQS[t]  = ((const float4*)GPQ)[t];
        ogS[t]   = ogG[(long)b * 128 + t];
        opS[t]   = opG[(long)b * 128 + t];
        pogS[t]  = pogG[(long)b * 128 + t];
        gbqS[t]  = gbq[t];
        vg2S[t]  = -2.f * vgG[t];
        vp2S[t]  = -2.f * vpG[t];
        hS[t] = 0.f; cS[t] = 0.f;
        visitedS[t] = 0;
    }
    WihS[t] = ((const float4*)WihNE4)[t];
    g0S[t] = g0[t];
    bcS[t] = bc[t];
    if (t == 0) sumvpS = sumvpG[0];
    __syncthreads();

    for (int step = 0; step < TSTEPS; step++) {
        // ---- G: one gate per thread; Whh panel stream (coalesced float4) ----
        {
            float ihp;
            if (step == 0) {
                ihp = g0S[t];
            } else {
                float4 xd = dataS[selS];
                float4 w = WihS[t];
                ihp = xd.x * w.x + xd.y * w.y + xd.z * w.z + xd.w * w.w;
            }
            ihp += bcS[t];
            const float4* wp = (const float4*)WhhP + t;
            float a0 = 0.f, a1 = 0.f, a2 = 0.f, a3 = 0.f;
#pragma unroll 8
            for (int kb = 0; kb < 32; kb++) {
                float4 w = wp[kb * 512];
                a0 += w.x * hS[4 * kb];     a1 += w.y * hS[4 * kb + 1];
                a2 += w.z * hS[4 * kb + 2]; a3 += w.w * hS[4 * kb + 3];
            }
            gatesS[t] = ihp + (a0 + a1) + (a2 + a3);
        }
        __syncthreads();
        // ---- L: LSTM pointwise (i,f,g,o) ----
        if (t < 128) {
            float ig  = fast_sig(gatesS[t]);
            float fg  = fast_sig(gatesS[128 + t]);
            float gg  = fast_tanh(gatesS[256 + t]);
            float og_ = fast_sig(gatesS[384 + t]);
            float cn = fg * cS[t] + ig * gg;
            cS[t] = cn;
            hS[t] = og_ * fast_tanh(cn);
        }
        __syncthreads();
        // ---- Q: glimpse query, full dot per o; writes prescaled qe ----
        if (t < 128) {
            const float4* wp = (const float4*)gWqP + t;
            float a0 = 0.f, a1 = 0.f, a2 = 0.f, a3 = 0.f;
#pragma unroll 8
            for (int ib = 0; ib < 32; ib++) {
                float4 w = wp[ib * 128];
                a0 += w.x * hS[4 * ib];     a1 += w.y * hS[4 * ib + 1];
                a2 += w.z * hS[4 * ib + 2]; a3 += w.w * hS[4 * ib + 3];
            }
            float q = (a0 + a1) + (a2 + a3) + gbqS[t];
            qeS[t] = CT * (q + ogS[t]);
        }
        __syncthreads();
        // ---- GL: glimpse logits, 4-way d-split; x prescaled, -2v folded ----
        {
            int n = t & 127, q4 = t >> 7, d0 = q4 * 32;
            float4 dn = dataS[n];
            float acc = 0.f;
#pragma unroll 8
            for (int j = 0; j < 32; j++) {
                int d = d0 + j;
                float4 qg = QgcS[d];
                float x = qeS[d] + dn.x * qg.x + dn.y * qg.y + dn.z * qg.z + dn.w * qg.w;
                acc += vg2S[d] * frcp(1.f + fexp2(x));
            }
            lpart[q4][n] = acc;
        }
        __syncthreads();
        // ---- S: glimpse softmax + dp-reduce + pointer query (1 wave) ----
        if (t < 64) {
            float l0 = visitedS[t] ? NEGV
                     : (lpart[0][t] + lpart[1][t]) + (lpart[2][t] + lpart[3][t]);
            float l1 = visitedS[t + 64] ? NEGV
                     : (lpart[0][t + 64] + lpart[1][t + 64]) + (lpart[2][t + 64] + lpart[3][t + 64]);
            float m = fmaxf(l0, l1);
            for (int off = 32; off; off >>= 1) m = fmaxf(m, __shfl_xor(m, off, 64));
            float p0 = fast_exp(l0 - m), p1 = fast_exp(l1 - m);
            float s = p0 + p1;
            float4 d0v = dataS[t], d1v = dataS[t + 64];
            float q0 = p0 * d0v.x + p1 * d1v.x;
            float q1 = p0 * d0v.y + p1 * d1v.y;
            float q2 = p0 * d0v.z + p1 * d1v.z;
            float q3 = p0 * d0v.w + p1 * d1v.w;
            for (int off = 32; off; off >>= 1) {
                s  += __shfl_xor(s, off, 64);
                q0 += __shfl_xor(q0, off, 64);
                q1 += __shfl_xor(q1, off, 64);
                q2 += __shfl_xor(q2, off, 64);
                q3 += __shfl_xor(q3, off, 64);
            }
            float inv = frcp(s);
            q0 *= inv; q1 *= inv; q2 *= inv; q3 *= inv;
            float4 gA = GPQS[t];
            qepS[t] = CT * (q0 * gA.x + q1 * gA.y + q2 * gA.z + q3 * gA.w
                            + pogS[t] + opS[t]);
            float4 gB = GPQS[t + 64];
            qepS[t + 64] = CT * (q0 * gB.x + q1 * gB.y + q2 * gB.z + q3 * gB.w
                                 + pogS[t + 64] + opS[t + 64]);
        }
        __syncthreads();
        // ---- PL: pointer logits ----
        {
            int n = t & 127, q4 = t >> 7, d0 = q4 * 32;
            float4 dn = dataS[n];
            float acc = 0.f;
#pragma unroll 8
            for (int j = 0; j < 32; j++) {
                int d = d0 + j;
                float4 qp = QpcS[d];
                float x = qepS[d] + dn.x * qp.x + dn.y * qp.y + dn.z * qp.z + dn.w * qp.w;
                acc += vp2S[d] * frcp(1.f + fexp2(x));
            }
            lpart[q4][n] = acc;
        }
        __syncthreads();
        // ---- P: 10*tanh, mask, log_softmax, out, argmax (1 wave) ----
        if (t < 64) {
            float s0 = sumvpS + (lpart[0][t] + lpart[1][t]) + (lpart[2][t] + lpart[3][t]);
            float s1 = sumvpS + (lpart[0][t + 64] + lpart[1][t + 64])
                              + (lpart[2][t + 64] + lpart[3][t + 64]);
            float l0 = visitedS[t]      ? NEGV : 10.f * fast_tanh(s0);
            float l1 = visitedS[t + 64] ? NEGV : 10.f * fast_tanh(s1);
            float m = fmaxf(l0, l1);
            for (int off = 32; off; off >>= 1) m = fmaxf(m, __shfl_xor(m, off, 64));
            float p0 = fast_exp(l0 - m), p1 = fast_exp(l1 - m);
            float s = p0 + p1;
            for (int off = 32; off; off >>= 1) s += __shfl_xor(s, off, 64);
            float lse = m + fast_log(s);
            float* outp = out + ((long)step * BATCH + b) * NREG;
            outp[t] = l0 - lse;
            outp[t + 64] = l1 - lse;
            float v; int idx;
            if (l1 > l0) { v = l1; idx = t + 64; } else { v = l0; idx = t; }
            for (int off = 32; off; off >>= 1) {
                float ov = __shfl_xor(v, off, 64);
                int   oi = __shfl_xor(idx, off, 64);
                if (ov > v || (ov == v && oi < idx)) { v = ov; idx = oi; }
            }
            if (t == 0) { selS = idx; visitedS[idx] = 1; }
        }
        __syncthreads();
    }
}

// ---------------- host launcher ----------------
extern "C" void kernel_launch(void* const* d_in, const int* in_sizes, int n_in,
                              void* d_out, int out_size, void* d_ws, size_t ws_size,
                              hipStream_t stream) {
    const float* data = (const float*)d_in[0];
    const float* NE   = (const float*)d_in[1];
    const float* init = (const float*)d_in[2];
    const float* W1w = (const float*)d_in[3];  const float* W1b = (const float*)d_in[4];
    const float* W2w = (const float*)d_in[5];  const float* W2b = (const float*)d_in[6];
    const float* W3w = (const float*)d_in[7];  const float* W3b = (const float*)d_in[8];
    const float* A1w = (const float*)d_in[9];  const float* A1b = (const float*)d_in[10];
    const float* A2w = (const float*)d_in[11]; const float* A2b = (const float*)d_in[12];
    const float* A3w = (const float*)d_in[13]; const float* A3b = (const float*)d_in[14];
    const float* r1  = (const float*)d_in[15];
    const float* r2  = (const float*)d_in[16];
    const float* r3  = (const float*)d_in[17];
    const float* Wih = (const float*)d_in[18]; const float* Whh = (const float*)d_in[19];
    const float* bih = (const float*)d_in[20]; const float* bhh = (const float*)d_in[21];
    const float* pWq = (const float*)d_in[22]; const float* pbq = (const float*)d_in[23];
    const float* pWr = (const float*)d_in[24]; const float* pbr = (const float*)d_in[25];
    const float* pv  = (const float*)d_in[26];
    const float* gWq = (const float*)d_in[27]; const float* gbq = (const float*)d_in[28];
    const float* gWr = (const float*)d_in[29]; const float* gbr = (const float*)d_in[30];
    const float* gv  = (const float*)d_in[31];
    float* out = (float*)d_out;

    float* ws     = (float*)d_ws;
    float* WhhP   = ws;                    // 65536
    float* gWqP   = WhhP + 65536;          // 16384
    float* WihNE4 = gWqP + 16384;          // 2048
    float* g0     = WihNE4 + 2048;         // 512
    float* bc     = g0 + 512;              // 512
    float* Qgc    = bc + 512;              // 512
    float* Qpc    = Qgc + 512;             // 512
    float* GPQ    = Qpc + 512;             // 512
    float* og     = GPQ + 512;             // 65536
    float* op     = og + 65536;            // 65536
    float* pog    = op + 65536;            // 65536
    float* sumvp  = pog + 65536;           // 4

    k_misc<<<148, 256, 0, stream>>>(Whh, gWq, Wih, NE, init, bih, bhh,
                                    W1w, W1b, W2w, W2b, W3w, W3b,
                                    A1w, A1b, A2w, A2b, A3w, A3b,
                                    gWr, gbr, pWr, pbr, pWq, pbq,
                                    r1, r2, r3, pv, data,
                                    WhhP, gWqP, WihNE4, g0, bc, sumvp,
                                    Qgc, Qpc, GPQ, og, op, pog);
    k_decode<<<BATCH, 512, 0, stream>>>(data, WhhP, gWqP, WihNE4, g0, bc,
                                        Qgc, Qpc, GPQ, og, op, pog,
                                        gbq, gv, pv, sumvp, out);
}